// Round 2
// baseline (647.519 us; speedup 1.0000x reference)
//
#include <hip/hip_runtime.h>
#include <hip/hip_bf16.h>

// BitNet b1.58 linear: out = scale * (x @ clip(round(w/scale),-1,1)^T)
// scale = 1e-4 + mean(|w|).  M=8192, N=8192, K=2048, fp32 in/out.
// Pipeline: deterministic 2-stage |w| reduction (scratch in d_out tail) ->
// prep: q = bf16 in {-1,0,1}, xs = bf16(x*scale)  (scale folded into A) ->
// bf16 MFMA GEMM out = xs @ q^T (m97 structure + XCD swizzle).
// d_ws usage: exactly 64 MiB (qw 32 MiB | xs 32 MiB). Nothing else.

typedef __bf16 bf16x8 __attribute__((ext_vector_type(8)));
typedef float  f32x4  __attribute__((ext_vector_type(4)));

#define GAS __attribute__((address_space(1)))
#define LAS __attribute__((address_space(3)))

static constexpr int  M_DIM = 8192;
static constexpr int  N_DIM = 8192;
static constexpr int  K_DIM = 2048;
static constexpr long NELEM = 16777216;   // elements in x and in w

// --------------------------------------------- stage 1: per-block |w| sums
__global__ void absmean1_kernel(const float* __restrict__ w, double* __restrict__ partials) {
    double s = 0.0;
    const float4* w4 = (const float4*)w;
    const int n4 = (int)(NELEM / 4);
    for (int i = blockIdx.x * blockDim.x + threadIdx.x; i < n4; i += gridDim.x * blockDim.x) {
        float4 v = w4[i];
        s += (double)fabsf(v.x) + (double)fabsf(v.y) + (double)fabsf(v.z) + (double)fabsf(v.w);
    }
    #pragma unroll
    for (int off = 32; off > 0; off >>= 1) s += __shfl_down(s, off);
    __shared__ double wsum[4];
    if ((threadIdx.x & 63) == 0) wsum[threadIdx.x >> 6] = s;
    __syncthreads();
    if (threadIdx.x == 0) partials[blockIdx.x] = wsum[0] + wsum[1] + wsum[2] + wsum[3];
}

// --------------------------------------------- stage 2: 2048 partials -> scale
__global__ void absmean2_kernel(const double* __restrict__ partials, float* __restrict__ scale_out) {
    double s = 0.0;
    #pragma unroll
    for (int j = 0; j < 8; ++j) s += partials[threadIdx.x + 256 * j];
    #pragma unroll
    for (int off = 32; off > 0; off >>= 1) s += __shfl_down(s, off);
    __shared__ double wsum[4];
    if ((threadIdx.x & 63) == 0) wsum[threadIdx.x >> 6] = s;
    __syncthreads();
    if (threadIdx.x == 0) {
        double total = wsum[0] + wsum[1] + wsum[2] + wsum[3];
        scale_out[0] = (float)(1.0e-4 + total * (1.0 / 16777216.0));
    }
}

// ----------------------------- prep: q = quantized w (bf16), xs = bf16(x*scale)
__global__ void prep_kernel(const float* __restrict__ x, const float* __restrict__ w,
                            const float* __restrict__ scale_in,
                            __bf16* __restrict__ xs, __bf16* __restrict__ qw) {
    const float scale = scale_in[0];
    const int n8 = (int)(NELEM / 8);
    const float4* x4 = (const float4*)x;
    const float4* w4 = (const float4*)w;
    for (int i = blockIdx.x * blockDim.x + threadIdx.x; i < n8; i += gridDim.x * blockDim.x) {
        float4 a0 = x4[2 * i], a1 = x4[2 * i + 1];
        bf16x8 xv;
        xv[0] = (__bf16)(a0.x * scale); xv[1] = (__bf16)(a0.y * scale);
        xv[2] = (__bf16)(a0.z * scale); xv[3] = (__bf16)(a0.w * scale);
        xv[4] = (__bf16)(a1.x * scale); xv[5] = (__bf16)(a1.y * scale);
        xv[6] = (__bf16)(a1.z * scale); xv[7] = (__bf16)(a1.w * scale);
        *(bf16x8*)(xs + 8l * i) = xv;

        float4 b0 = w4[2 * i], b1 = w4[2 * i + 1];
        float wv[8] = {b0.x, b0.y, b0.z, b0.w, b1.x, b1.y, b1.z, b1.w};
        bf16x8 qv;
        #pragma unroll
        for (int e = 0; e < 8; ++e) {
            float r = rintf(wv[e] / scale);           // fp32 divide+RNE round = ref semantics
            r = fminf(1.0f, fmaxf(-1.0f, r));
            qv[e] = (__bf16)r;                         // {-1,0,1} exact in bf16
        }
        *(bf16x8*)(qw + 8l * i) = qv;
    }
}

// ------------------------------------------------------------------ GEMM
// C[m][n] = sum_k A[m][k] * B[n][k]   (A = xs MxK, B = qw NxK, both K-contig)
// 128x128 tile, BK=64, 4 waves (2x2), wave = 64x64 = 4x4 frags of 16x16x32.
// LDS: linear dest for global_load_lds; bank-conflict fix via pre-swizzled
// GLOBAL source chunk (chunk^row&7) + matching XOR on ds_read (rule #21).
__global__ __launch_bounds__(256, 2) void gemm_kernel(const __bf16* __restrict__ A,
                                                      const __bf16* __restrict__ B,
                                                      float* __restrict__ C) {
    __shared__ __bf16 As[128 * 64];
    __shared__ __bf16 Bs[128 * 64];

    const int tid  = threadIdx.x;
    const int lane = tid & 63;
    const int wid  = tid >> 6;
    const int wr   = wid >> 1;
    const int wc   = wid & 1;

    // XCD-aware bijective swizzle (nwg = 4096, divisible by 8)
    const int linear = blockIdx.y * gridDim.x + blockIdx.x;
    const int swzid  = (linear & 7) * 512 + (linear >> 3);
    const int bm = swzid >> 6;
    const int bn = swzid & 63;

    const int lrow   = lane >> 3;            // row within 8-row staging group
    const int lchunk = lane & 7;             // dest 16B chunk in 128B row
    const int schunk = lchunk ^ lrow;        // pre-swizzled source chunk

    const long a_row0 = (long)bm * 128 + wid * 32 + lrow;
    const long b_row0 = (long)bn * 128 + wid * 32 + lrow;

    f32x4 acc[4][4];
    #pragma unroll
    for (int i = 0; i < 4; ++i)
        #pragma unroll
        for (int j = 0; j < 4; ++j)
            acc[i][j] = f32x4{0.0f, 0.0f, 0.0f, 0.0f};

    const char* As_c = (const char*)As;
    const char* Bs_c = (const char*)Bs;
    const int frow_a = wr * 64 + (lane & 15);
    const int frow_b = wc * 64 + (lane & 15);
    const int fcolb  = (lane >> 4) << 4;
    const int swz    = (lane & 7) << 4;      // XOR matches staging permutation

    for (int kt = 0; kt < K_DIM / 64; ++kt) {
        const int k0 = kt * 64;
        #pragma unroll
        for (int i = 0; i < 4; ++i) {
            const __bf16* ga = A + (a_row0 + i * 8) * K_DIM + k0 + schunk * 8;
            __builtin_amdgcn_global_load_lds((const GAS unsigned int*)ga,
                (LAS unsigned int*)(As + (wid * 32 + i * 8) * 64), 16, 0, 0);
            const __bf16* gb = B + (b_row0 + i * 8) * K_DIM + k0 + schunk * 8;
            __builtin_amdgcn_global_load_lds((const GAS unsigned int*)gb,
                (LAS unsigned int*)(Bs + (wid * 32 + i * 8) * 64), 16, 0, 0);
        }
        __syncthreads();

        #pragma unroll
        for (int kk = 0; kk < 2; ++kk) {
            bf16x8 af[4], bg[4];
            #pragma unroll
            for (int i = 0; i < 4; ++i)
                af[i] = *(const bf16x8*)(As_c + (frow_a + i * 16) * 128 + ((fcolb | (kk << 6)) ^ swz));
            #pragma unroll
            for (int j = 0; j < 4; ++j)
                bg[j] = *(const bf16x8*)(Bs_c + (frow_b + j * 16) * 128 + ((fcolb | (kk << 6)) ^ swz));
            #pragma unroll
            for (int i = 0; i < 4; ++i)
                #pragma unroll
                for (int j = 0; j < 4; ++j)
                    acc[i][j] = __builtin_amdgcn_mfma_f32_16x16x32_bf16(af[i], bg[j], acc[i][j], 0, 0, 0);
        }
        __syncthreads();
    }

    // C/D layout: col = lane&15, row = (lane>>4)*4 + reg   [verified m89]
    const int crow = (lane >> 4) * 4;
    const int ccol = lane & 15;
    #pragma unroll
    for (int i = 0; i < 4; ++i) {
        #pragma unroll
        for (int j = 0; j < 4; ++j) {
            #pragma unroll
            for (int r = 0; r < 4; ++r) {
                const long gm = (long)bm * 128 + wr * 64 + i * 16 + crow + r;
                const long gn = (long)bn * 128 + wc * 64 + j * 16 + ccol;
                C[gm * N_DIM + gn] = acc[i][j][r];
            }
        }
    }
}

// ---------------------------------------------------------------- launcher
extern "C" void kernel_launch(void* const* d_in, const int* in_sizes, int n_in,
                              void* d_out, int out_size, void* d_ws, size_t ws_size,
                              hipStream_t stream) {
    const float* x = (const float*)d_in[0];   // (4,2048,2048) fp32
    const float* w = (const float*)d_in[1];   // (8192,2048)  fp32
    float* out = (float*)d_out;               // (4,2048,8192) fp32

    // d_ws: qw bf16 (32 MiB) | xs bf16 (32 MiB)  == 64 MiB total, no overflow
    char* ws = (char*)d_ws;
    __bf16* qw = (__bf16*)ws;
    __bf16* xs = (__bf16*)(ws + 33554432);

    // reduction scratch lives in the TAIL of d_out; gemm overwrites it later
    char* tail = (char*)d_out + (size_t)out_size * sizeof(float);
    double* partials = (double*)(tail - 16384);          // 2048 doubles
    float* scalep    = (float*)(tail - 16448);           // 1 float (64B aligned)

    absmean1_kernel<<<2048, 256, 0, stream>>>(w, partials);
    absmean2_kernel<<<1, 256, 0, stream>>>(partials, scalep);
    prep_kernel<<<2048, 256, 0, stream>>>(x, w, scalep, xs, qw);
    dim3 grid(N_DIM / 128, M_DIM / 128);                 // (64, 64)
    gemm_kernel<<<grid, 256, 0, stream>>>(xs, qw, out);
}

// Round 4
// 582.027 us; speedup vs baseline: 1.1125x; 1.1125x over previous
//
#include <hip/hip_runtime.h>
#include <hip/hip_bf16.h>

// BitNet b1.58 linear: out = scale * (x @ clip(round(w/scale),-1,1)^T)
// scale = 1e-4 + mean(|w|).  M=8192, N=8192, K=2048, fp32 in/out.
// Pipeline: deterministic 2-stage |w| reduction (scratch in d_out tail) ->
// prep (q = bf16 {-1,0,1}, xs = bf16(x*scale)) ->
// 256x256 8-phase bf16 MFMA GEMM (T2 swizzle + T3/T4 counted vmcnt + T5 setprio).

typedef __bf16 bf16x8 __attribute__((ext_vector_type(8)));
typedef float  f32x4  __attribute__((ext_vector_type(4)));

#define GAS __attribute__((address_space(1)))
#define LAS __attribute__((address_space(3)))

static constexpr int  M_DIM = 8192;
static constexpr int  N_DIM = 8192;
static constexpr int  K_DIM = 2048;
static constexpr long NELEM = 16777216;

// --------------------------------------------- stage 1: per-block |w| sums
__global__ void absmean1_kernel(const float* __restrict__ w, double* __restrict__ partials) {
    double s = 0.0;
    const float4* w4 = (const float4*)w;
    const int n4 = (int)(NELEM / 4);
    for (int i = blockIdx.x * blockDim.x + threadIdx.x; i < n4; i += gridDim.x * blockDim.x) {
        float4 v = w4[i];
        s += (double)fabsf(v.x) + (double)fabsf(v.y) + (double)fabsf(v.z) + (double)fabsf(v.w);
    }
    #pragma unroll
    for (int off = 32; off > 0; off >>= 1) s += __shfl_down(s, off);
    __shared__ double wsum[4];
    if ((threadIdx.x & 63) == 0) wsum[threadIdx.x >> 6] = s;
    __syncthreads();
    if (threadIdx.x == 0) partials[blockIdx.x] = wsum[0] + wsum[1] + wsum[2] + wsum[3];
}

// --------------------------------------------- stage 2: partials -> scale
__global__ void absmean2_kernel(const double* __restrict__ partials, float* __restrict__ scale_out) {
    double s = 0.0;
    #pragma unroll
    for (int j = 0; j < 8; ++j) s += partials[threadIdx.x + 256 * j];
    #pragma unroll
    for (int off = 32; off > 0; off >>= 1) s += __shfl_down(s, off);
    __shared__ double wsum[4];
    if ((threadIdx.x & 63) == 0) wsum[threadIdx.x >> 6] = s;
    __syncthreads();
    if (threadIdx.x == 0) {
        double total = wsum[0] + wsum[1] + wsum[2] + wsum[3];
        scale_out[0] = (float)(1.0e-4 + total * (1.0 / 16777216.0));
    }
}

// ----------------------------- prep: qw = quantized w (bf16), xs = bf16(x*scale)
__global__ void prep_kernel(const float* __restrict__ x, const float* __restrict__ w,
                            const float* __restrict__ scale_in,
                            __bf16* __restrict__ xs, __bf16* __restrict__ qw) {
    const float scale = scale_in[0];
    const int n8 = (int)(NELEM / 8);
    const float4* x4 = (const float4*)x;
    const float4* w4 = (const float4*)w;
    for (int i = blockIdx.x * blockDim.x + threadIdx.x; i < n8; i += gridDim.x * blockDim.x) {
        float4 a0 = x4[2 * i], a1 = x4[2 * i + 1];
        bf16x8 xv;
        xv[0] = (__bf16)(a0.x * scale); xv[1] = (__bf16)(a0.y * scale);
        xv[2] = (__bf16)(a0.z * scale); xv[3] = (__bf16)(a0.w * scale);
        xv[4] = (__bf16)(a1.x * scale); xv[5] = (__bf16)(a1.y * scale);
        xv[6] = (__bf16)(a1.z * scale); xv[7] = (__bf16)(a1.w * scale);
        *(bf16x8*)(xs + 8l * i) = xv;

        float4 b0 = w4[2 * i], b1 = w4[2 * i + 1];
        float wv[8] = {b0.x, b0.y, b0.z, b0.w, b1.x, b1.y, b1.z, b1.w};
        bf16x8 qv;
        #pragma unroll
        for (int e = 0; e < 8; ++e) {
            float r = rintf(wv[e] / scale);
            r = fminf(1.0f, fmaxf(-1.0f, r));
            qv[e] = (__bf16)r;
        }
        *(bf16x8*)(qw + 8l * i) = qv;
    }
}

// ------------------------------------------------------------------ GEMM
// C[m][n] = sum_k A[m][k]*B[n][k].  256x256 tile, BK=64, 512 thr = 8 waves (2Mx4N).
// LDS 128KiB: [dbuf 2][A/B][256 rows][64 cols] bf16, 16B chunks permuted chunk^(row&7)
// (linear dest for global_load_lds, pre-swizzled global source, swizzled ds_read).
// 8 phases / 2 K-tiles; vmcnt(2) only at phases 4 & 8; setprio around MFMA cluster.
// Staging schedule (region overwritten only after its last-reader phase's barrier):
//   q0:(d0,mq0,nq0) stg d1.A.t1(kt1) | q1:(d0,1,0) stg d1.B.h0(kt1) | q2:(d0,0,1) stg d1.B.h1(kt1)
//   q3:(d0,1,1) stg d0.A.t0(kt2) +vmcnt(2) | q4:(d1,0,0) stg d0.B.h0(kt2) | q5:(d1,1,0) stg d0.B.h1(kt2)
//   q6:(d1,0,1) stg d0.A.t1(kt2) | q7:(d1,1,1) stg d1.A.t0(kt3) +vmcnt(2)

#define STAGE_A(dd, t, kt) do { \
    _Pragma("unroll") for (int _h = 0; _h < 2; ++_h) { \
        const __bf16* _g = A + (long)(bm * 256 + _h * 128 + (t) * 64 + (tid >> 3)) * K_DIM \
                             + (kt) * 64 + schunk * 8; \
        __builtin_amdgcn_global_load_lds((const GAS unsigned int*)_g, \
            (LAS unsigned int*)(lds + (dd) * 32768 + _h * 8192 + (t) * 4096 + wid * 512), 16, 0, 0); \
    } } while (0)

#define STAGE_B(dd, h, kt) do { \
    _Pragma("unroll") for (int _t = 0; _t < 2; ++_t) { \
        const __bf16* _g = B + (long)(bn * 256 + (h) * 128 + _t * 64 + (tid >> 3)) * K_DIM \
                             + (kt) * 64 + schunk * 8; \
        __builtin_amdgcn_global_load_lds((const GAS unsigned int*)_g, \
            (LAS unsigned int*)(lds + (dd) * 32768 + 16384 + (h) * 8192 + _t * 4096 + wid * 512), 16, 0, 0); \
    } } while (0)

#define VM2 asm volatile("s_waitcnt vmcnt(2)" ::: "memory")

#define PHASE(dd, mq, nq, STG, DOVM) do { \
    bf16x8 af[4][2], bg[2][2]; \
    _Pragma("unroll") for (int mi = 0; mi < 4; ++mi) \
        _Pragma("unroll") for (int kk = 0; kk < 2; ++kk) \
            af[mi][kk] = *(const bf16x8*)(L + (dd) * 65536 \
                + (wr * 128 + (mq) * 64 + mi * 16 + l15) * 128 + (kk ? kb1 : kb0)); \
    _Pragma("unroll") for (int nj = 0; nj < 2; ++nj) \
        _Pragma("unroll") for (int kk = 0; kk < 2; ++kk) \
            bg[nj][kk] = *(const bf16x8*)(L + (dd) * 65536 + 32768 \
                + (wc * 64 + (nq) * 32 + nj * 16 + l15) * 128 + (kk ? kb1 : kb0)); \
    STG; \
    __builtin_amdgcn_s_barrier(); \
    asm volatile("s_waitcnt lgkmcnt(0)" ::: "memory"); \
    __builtin_amdgcn_sched_barrier(0); \
    __builtin_amdgcn_s_setprio(1); \
    _Pragma("unroll") for (int mi = 0; mi < 4; ++mi) \
        _Pragma("unroll") for (int nj = 0; nj < 2; ++nj) \
            _Pragma("unroll") for (int kk = 0; kk < 2; ++kk) \
                acc[(mq) * 4 + mi][(nq) * 2 + nj] = __builtin_amdgcn_mfma_f32_16x16x32_bf16( \
                    af[mi][kk], bg[nj][kk], acc[(mq) * 4 + mi][(nq) * 2 + nj], 0, 0, 0); \
    __builtin_amdgcn_s_setprio(0); \
    DOVM; \
    __builtin_amdgcn_s_barrier(); \
} while (0)

__global__ __launch_bounds__(512, 2) void gemm_kernel(const __bf16* __restrict__ A,
                                                      const __bf16* __restrict__ B,
                                                      float* __restrict__ C) {
    __shared__ __bf16 lds[65536];   // 128 KiB: [d][A/B][256][64]

    const int tid  = threadIdx.x;
    const int lane = tid & 63;
    const int wid  = tid >> 6;       // 0..7
    const int wr   = wid >> 2;       // 0..1 -> M half (128 rows)
    const int wc   = wid & 3;        // 0..3 -> N quarter (64 cols)
    const int l15  = lane & 15;

    // XCD-aware bijective swizzle (nwg = 1024, %8 == 0)
    const int linear = blockIdx.y * gridDim.x + blockIdx.x;
    const int swzid  = (linear & 7) * 128 + (linear >> 3);
    const int bm = swzid >> 5;       // 0..31
    const int bn = swzid & 31;       // 0..31

    // staging: lane covers LDS row tid>>3, chunk tid&7 of an 8KB inst-region;
    // global source chunk pre-swizzled so LDS[row][c] = G[row][c^(row&7)]
    const int schunk = (tid & 7) ^ ((tid >> 3) & 7);

    // fragment-read byte offsets within a 128B row (matching swizzle)
    const int swz = (lane & 7) << 4;
    const int khi = ((lane >> 4) & 3) << 4;
    const int kb0 = khi ^ swz;
    const int kb1 = (khi | 64) ^ swz;
    const char* L = (const char*)lds;

    f32x4 acc[8][4];
    #pragma unroll
    for (int i = 0; i < 8; ++i)
        #pragma unroll
        for (int j = 0; j < 4; ++j)
            acc[i][j] = f32x4{0.0f, 0.0f, 0.0f, 0.0f};

    // prologue: tile0 -> dbuf0 (8 loads), tile1.A.t0 -> dbuf1 (2 loads)
    STAGE_A(0, 0, 0);
    STAGE_A(0, 1, 0);
    STAGE_B(0, 0, 0);
    STAGE_B(0, 1, 0);
    STAGE_A(1, 0, 1);
    VM2;                                  // drain 8 oldest = tile0 resident
    __builtin_amdgcn_s_barrier();

    const int NITER = K_DIM / 128;        // 16 iterations, 2 K-tiles each
    for (int i = 0; i < NITER; ++i) {
        const int kt1 = 2 * i + 1;
        const int kt2 = (2 * i + 2) & 31; // wrap: redundant harmless loads on last iter
        const int kt3 = (2 * i + 3) & 31;
        PHASE(0, 0, 0, STAGE_A(1, 1, kt1), );
        PHASE(0, 1, 0, STAGE_B(1, 0, kt1), );
        PHASE(0, 0, 1, STAGE_B(1, 1, kt1), );
        PHASE(0, 1, 1, STAGE_A(0, 0, kt2), VM2);
        PHASE(1, 0, 0, STAGE_B(0, 0, kt2), );
        PHASE(1, 1, 0, STAGE_B(0, 1, kt2), );
        PHASE(1, 0, 1, STAGE_A(0, 1, kt2), );
        PHASE(1, 1, 1, STAGE_A(1, 0, kt3), VM2);
    }

    // epilogue: C/D layout col = lane&15, row = (lane>>4)*4 + reg  [m89]
    const int crow = (lane >> 4) << 2;
    #pragma unroll
    for (int mi = 0; mi < 8; ++mi) {
        #pragma unroll
        for (int nj = 0; nj < 4; ++nj) {
            #pragma unroll
            for (int r = 0; r < 4; ++r) {
                const long gm = (long)bm * 256 + wr * 128 + mi * 16 + crow + r;
                const long gn = (long)bn * 256 + wc * 64 + nj * 16 + l15;
                C[gm * N_DIM + gn] = acc[mi][nj][r];
            }
        }
    }
}

// ---------------------------------------------------------------- launcher
extern "C" void kernel_launch(void* const* d_in, const int* in_sizes, int n_in,
                              void* d_out, int out_size, void* d_ws, size_t ws_size,
                              hipStream_t stream) {
    const float* x = (const float*)d_in[0];   // (4,2048,2048) fp32
    const float* w = (const float*)d_in[1];   // (8192,2048)  fp32
    float* out = (float*)d_out;               // (4,2048,8192) fp32

    // d_ws: qw bf16 (32 MiB) | xs bf16 (32 MiB) == 64 MiB, no overflow
    char* ws = (char*)d_ws;
    __bf16* qw = (__bf16*)ws;
    __bf16* xs = (__bf16*)(ws + 33554432);

    // reduction scratch in the TAIL of d_out; gemm overwrites it afterwards
    char* tail = (char*)d_out + (size_t)out_size * sizeof(float);
    double* partials = (double*)(tail - 16384);   // 2048 doubles
    float* scalep    = (float*)(tail - 16448);

    absmean1_kernel<<<2048, 256, 0, stream>>>(w, partials);
    absmean2_kernel<<<1, 256, 0, stream>>>(partials, scalep);
    prep_kernel<<<2048, 256, 0, stream>>>(x, w, scalep, xs, qw);
    dim3 grid(32, 32);
    gemm_kernel<<<grid, 512, 0, stream>>>(xs, qw, out);
}